// Round 2
// baseline (189.774 us; speedup 1.0000x reference)
//
#include <hip/hip_runtime.h>
#include <stdint.h>

constexpr int B = 4;
constexpr int L = 2048;
constexpr int H = 8;
constexpr int D = 64;
constexpr int S = 40;    // sampled keys per query
constexpr int U = 40;    // top-k queries
constexpr int HD = H * D;          // 512
constexpr int NSEG = 8;            // top-k segments per (b,h)
constexpr int SEGL = L / NSEG;     // 256
constexpr int NC = 64;             // cumsum chunks
constexpr int CL = L / NC;         // 32

// monotone float->uint mapping: larger float => larger uint
__device__ __forceinline__ unsigned mono(float v) {
    unsigned u = __float_as_uint(v);
    return (u & 0x80000000u) ? ~u : (u | 0x80000000u);
}

typedef float f4v __attribute__((ext_vector_type(4)));

__device__ __forceinline__ float4 ntload4(const float4* p) {
    f4v v = __builtin_nontemporal_load((const f4v*)p);
    return make_float4(v.x, v.y, v.z, v.w);
}

// ---------------------------------------------------------------------------
// K1: M[b,h,q] = max_s(Q.K_sample) - sum_s(Q.K_sample)/L for ALL 8 heads at
// once. One wave per (b,q): lane = h*8+dd covers dims [8*lane..8*lane+7] of
// the contiguous 2 KB row K[b,ki,:,:]. Q loads are non-temporal (read-once
// stream) so they don't evict the K slab from the per-XCD L2.
// XCD swizzle: b = (blockIdx%8)>>1 pins each b's 4 MB K slab to 2 XCDs.
// ---------------------------------------------------------------------------
__global__ __launch_bounds__(256) void k_scores(
    const float4* __restrict__ Q4, const float4* __restrict__ K4,
    const int* __restrict__ idxs, float* __restrict__ M)
{
    int i = blockIdx.x;                 // 0..2047
    int xcd = i & 7;
    int b = xcd >> 1;
    int qc = (i >> 3) * 2 + (xcd & 1);  // 0..511
    int w = threadIdx.x >> 6;
    int lane = threadIdx.x & 63;
    int q = qc * 4 + w;
    int h = lane >> 3;
    int dd = lane & 7;

    const float4* qrow = Q4 + (size_t)(b * L + q) * 128;
    float4 qa = ntload4(qrow + 2 * lane);
    float4 qb = ntload4(qrow + 2 * lane + 1);

    int v_idx = idxs[q * S + (lane < S ? lane : 0)];

    const float4* kbase = K4 + (size_t)b * L * 128;
    float mx = -INFINITY, sm = 0.f;
    #pragma unroll 8
    for (int s = 0; s < S; ++s) {
        int ki = __shfl(v_idx, s);
        const float4* krow = kbase + (size_t)ki * 128;
        float4 ka = krow[2 * lane], kb = krow[2 * lane + 1];
        float d = qa.x * ka.x + qa.y * ka.y + qa.z * ka.z + qa.w * ka.w
                + qb.x * kb.x + qb.y * kb.y + qb.z * kb.z + qb.w * kb.w;
        d += __shfl_xor(d, 1);
        d += __shfl_xor(d, 2);
        d += __shfl_xor(d, 4);
        mx = fmaxf(mx, d);
        sm += d;
    }
    if (dd == 0)
        M[(b * 8 + h) * L + q] = mx - sm * (1.0f / (float)L);
}

// ---------------------------------------------------------------------------
// K2: fused per-segment top-40 (8 waves, one per segment, candidates to LDS)
// + merge 320->top-40 + 40x40 triangle attention. One block per (b,h).
// Also zeroes the query flags.
// ---------------------------------------------------------------------------
__global__ __launch_bounds__(512) void k_topk_attn(
    const float* __restrict__ M, const float4* __restrict__ Q4,
    const float4* __restrict__ K4, const float4* __restrict__ V4,
    int* __restrict__ flags, float* __restrict__ upd)
{
    __shared__ unsigned long long cnd[NSEG * U];   // 320
    __shared__ int top_idx[U];
    __shared__ __align__(16) float Qs[U * 68];
    __shared__ __align__(16) float Ks[U * 68];
    __shared__ __align__(16) float Vs[U * 68];
    __shared__ float P[U * 41];

    int bh = blockIdx.x;
    int b = bh >> 3, h = bh & 7;
    int tid = threadIdx.x;
    int seg = tid >> 6, lane = tid & 63;

    // ---- phase A: per-segment exact top-40 by rank counting (1 wave/seg) ---
    int j0 = seg * SEGL + lane * 4;

    // zero query flags for this segment (coalesced int4)
    *(int4*)(flags + (size_t)bh * L + j0) = make_int4(0, 0, 0, 0);

    float4 v = *(const float4*)(M + (size_t)bh * L + j0);
    unsigned m[4] = { mono(v.x), mono(v.y), mono(v.z), mono(v.w) };
    int rank[4] = { 0, 0, 0, 0 };

    #pragma unroll 4
    for (int src = 0; src < 64; ++src) {
        #pragma unroll
        for (int slot = 0; slot < 4; ++slot) {
            unsigned bm = __shfl(m[slot], src);
            int bj = src * 4 + slot;
            #pragma unroll
            for (int s = 0; s < 4; ++s) {
                int myj = lane * 4 + s;
                rank[s] += (bm > m[s]) || (bm == m[s] && bj < myj);
            }
        }
    }
    #pragma unroll
    for (int s = 0; s < 4; ++s)
        if (rank[s] < U)
            cnd[seg * U + rank[s]] = ((unsigned long long)m[s] << 32)
                                   | (unsigned)(~(unsigned)(j0 + s));
    __syncthreads();

    // ---- phase B: top-40 of 320 candidates (keys unique => ranks unique) --
    {
        unsigned long long ka = cnd[tid < NSEG * U ? tid : 0];
        int ra = 0;
        for (int j = 0; j < NSEG * U; ++j) ra += (cnd[j] > ka);
        if (tid < NSEG * U && ra < U) top_idx[ra] = (int)(~(unsigned)ka);
    }
    __syncthreads();

    if (tid < U) flags[bh * L + top_idx[tid]] = tid + 1;

    // ---- phase C: stage K[0..39], V[0..39], Q[top_idx[r]] (stride 68) -----
    for (int i = tid; i < U * 16; i += 512) {
        int r = i >> 4, d4 = i & 15;
        size_t kvbase = ((size_t)(b * L + r) * H + h) * 16 + d4;
        *(float4*)(Ks + r * 68 + d4 * 4) = K4[kvbase];
        *(float4*)(Vs + r * 68 + d4 * 4) = V4[kvbase];
        *(float4*)(Qs + r * 68 + d4 * 4) =
            Q4[((size_t)(b * L + top_idx[r]) * H + h) * 16 + d4];
    }
    __syncthreads();

    // scores: S[r][k] for k <= r (causal over rank, per reference)
    const float scale = 0.125f;   // 1/sqrt(64)
    for (int p = tid; p < U * U; p += 512) {
        int r = p / U, k = p - r * U;
        if (k <= r) {
            float acc = 0.f;
            #pragma unroll
            for (int d = 0; d < D; d += 4) {
                float4 a = *(const float4*)(Qs + r * 68 + d);
                float4 c = *(const float4*)(Ks + k * 68 + d);
                acc += a.x * c.x + a.y * c.y + a.z * c.z + a.w * c.w;
            }
            P[r * 41 + k] = acc * scale;
        }
    }
    __syncthreads();

    // row softmax over k <= r
    if (tid < U) {
        int r = tid;
        float mval = -INFINITY;
        for (int k = 0; k <= r; ++k) mval = fmaxf(mval, P[r * 41 + k]);
        float ssum = 0.f;
        for (int k = 0; k <= r; ++k) {
            float e = expf(P[r * 41 + k] - mval);
            P[r * 41 + k] = e;
            ssum += e;
        }
        float inv = 1.f / ssum;
        for (int k = 0; k <= r; ++k) P[r * 41 + k] *= inv;
    }
    __syncthreads();

    // upd[r][d] = sum_{k<=r} P[r][k] * V[k][d]
    for (int t = tid; t < U * D; t += 512) {
        int r = t >> 6, d = t & 63;
        float acc = 0.f;
        for (int k = 0; k <= r; ++k) acc += P[r * 41 + k] * Vs[k * 68 + d];
        upd[((size_t)bh * U + r) * D + d] = acc;
    }
}

// ---------------------------------------------------------------------------
// K3: per-chunk sums of V along L (totals only, NOT scanned).
// ---------------------------------------------------------------------------
__global__ __launch_bounds__(512) void k_chunksum(
    const float* __restrict__ V, float* __restrict__ partial)
{
    int b = blockIdx.x >> 6;        // NC = 64
    int c = blockIdx.x & 63;
    int hd = threadIdx.x;
    const float* vp = V + ((size_t)(b * L + c * CL)) * HD + hd;
    float s = 0.f;
    #pragma unroll
    for (int l = 0; l < CL; ++l) s += vp[(size_t)l * HD];
    partial[((size_t)b * NC + c) * HD + hd] = s;
}

// ---------------------------------------------------------------------------
// K4: emit. Each block (b,c) computes its exclusive prefix by summing the
// c predecessor chunk totals (512 KB of partials -> L2-resident, redundant
// but cheap and deadlock-free), then emits cumsum with flagged rows
// replaced by upd. Ordering is purely by dispatch boundaries - no
// inter-block waiting anywhere.
// ---------------------------------------------------------------------------
__global__ __launch_bounds__(512) void k_out(
    const float* __restrict__ V, const float* __restrict__ partial,
    const int* __restrict__ flags, const float* __restrict__ upd,
    float* __restrict__ out)
{
    int b = blockIdx.x >> 6;
    int c = blockIdx.x & 63;
    int hd = threadIdx.x;
    int h = hd >> 6, d = hd & 63;

    // exclusive prefix over predecessor chunk totals
    float acc = 0.f;
    const float* pp = partial + (size_t)b * NC * HD + hd;
    for (int j = 0; j < c; ++j) acc += pp[(size_t)j * HD];

    const float* vp = V + ((size_t)(b * L + c * CL)) * HD + hd;
    float*       op = out + ((size_t)(b * L + c * CL)) * HD + hd;
    const int*   fp = flags + (b * H + h) * L + c * CL;
    const float* up = upd + (size_t)(b * H + h) * U * D + d;

    #pragma unroll 4
    for (int l = 0; l < CL; ++l) {
        acc += vp[(size_t)l * HD];
        int f = fp[l];
        float o = f ? up[(size_t)(f - 1) * D] : acc;
        __builtin_nontemporal_store(o, op + (size_t)l * HD);
    }
}

extern "C" void kernel_launch(void* const* d_in, const int* in_sizes, int n_in,
                              void* d_out, int out_size, void* d_ws, size_t ws_size,
                              hipStream_t stream)
{
    const float* Q   = (const float*)d_in[0];
    const float* K   = (const float*)d_in[1];
    const float* V   = (const float*)d_in[2];
    const int*  idxs = (const int*)d_in[3];
    float* out = (float*)d_out;

    char* ws = (char*)d_ws;
    float* M        = (float*)(ws);                 // B*H*L          = 256 KB
    int*   flags    = (int*)  (ws + 262144);        // B*H*L          = 256 KB
    float* upd      = (float*)(ws + 524288);        // B*H*U*D        = 320 KB
    float* partial  = (float*)(ws + 851968);        // B*NC*HD        = 512 KB

    k_scores    <<<B * L / 4, 256, 0, stream>>>((const float4*)Q, (const float4*)K, idxs, M);
    k_topk_attn <<<B * H,     512, 0, stream>>>(M, (const float4*)Q, (const float4*)K,
                                                (const float4*)V, flags, upd);
    k_chunksum  <<<B * NC,    512, 0, stream>>>(V, partial);
    k_out       <<<B * NC,    512, 0, stream>>>(V, partial, flags, upd, out);
}

// Round 3
// 182.443 us; speedup vs baseline: 1.0402x; 1.0402x over previous
//
#include <hip/hip_runtime.h>
#include <stdint.h>

constexpr int B = 4;
constexpr int L = 2048;
constexpr int H = 8;
constexpr int D = 64;
constexpr int S = 40;    // sampled keys per query
constexpr int U = 40;    // top-k queries
constexpr int HD = H * D;          // 512
constexpr int NSEG = 8;            // top-k segments per (b,h)
constexpr int SEGL = L / NSEG;     // 256
constexpr int NC = 64;             // cumsum chunks
constexpr int CL = L / NC;         // 32

// monotone float->uint mapping: larger float => larger uint
__device__ __forceinline__ unsigned mono(float v) {
    unsigned u = __float_as_uint(v);
    return (u & 0x80000000u) ? ~u : (u | 0x80000000u);
}

typedef float f4v __attribute__((ext_vector_type(4)));

__device__ __forceinline__ float4 ntload4(const float4* p) {
    f4v v = __builtin_nontemporal_load((const f4v*)p);
    return make_float4(v.x, v.y, v.z, v.w);
}

// ---------------------------------------------------------------------------
// K1: M[b,h,q] = max_s(Q.K_sample) - sum_s(Q.K_sample)/L for ALL 8 heads at
// once. One wave per (b,q): lane = h*8+dd covers dims [8*lane..8*lane+7] of
// the contiguous 2 KB row K[b,ki,:,:]. Q loads are non-temporal (read-once
// stream) so they don't evict the K slab from the per-XCD L2.
// XCD swizzle: b = (blockIdx%8)>>1 pins each b's 4 MB K slab to 2 XCDs.
// ---------------------------------------------------------------------------
__global__ __launch_bounds__(256) void k_scores(
    const float4* __restrict__ Q4, const float4* __restrict__ K4,
    const int* __restrict__ idxs, float* __restrict__ M)
{
    int i = blockIdx.x;                 // 0..2047
    int xcd = i & 7;
    int b = xcd >> 1;
    int qc = (i >> 3) * 2 + (xcd & 1);  // 0..511
    int w = threadIdx.x >> 6;
    int lane = threadIdx.x & 63;
    int q = qc * 4 + w;
    int h = lane >> 3;
    int dd = lane & 7;

    const float4* qrow = Q4 + (size_t)(b * L + q) * 128;
    float4 qa = ntload4(qrow + 2 * lane);
    float4 qb = ntload4(qrow + 2 * lane + 1);

    int v_idx = idxs[q * S + (lane < S ? lane : 0)];

    const float4* kbase = K4 + (size_t)b * L * 128;
    float mx = -INFINITY, sm = 0.f;
    #pragma unroll 8
    for (int s = 0; s < S; ++s) {
        int ki = __shfl(v_idx, s);
        const float4* krow = kbase + (size_t)ki * 128;
        float4 ka = krow[2 * lane], kb = krow[2 * lane + 1];
        float d = qa.x * ka.x + qa.y * ka.y + qa.z * ka.z + qa.w * ka.w
                + qb.x * kb.x + qb.y * kb.y + qb.z * kb.z + qb.w * kb.w;
        d += __shfl_xor(d, 1);
        d += __shfl_xor(d, 2);
        d += __shfl_xor(d, 4);
        mx = fmaxf(mx, d);
        sm += d;
    }
    if (dd == 0)
        M[(b * 8 + h) * L + q] = mx - sm * (1.0f / (float)L);
}

// ---------------------------------------------------------------------------
// K2: fused per-segment top-40 + merge + 40x40 triangle attention, one block
// per (b,h). This round: phases B..E rewritten fully lane-parallel with
// compile-time loop bounds (no serial softmax, no runtime-bound k<=r loops):
//   - merge: one candidate/thread, unrolled 320-scan
//   - scores: lane k = key k, transposed pad-65 K tile (conflict-free),
//     b128 broadcast Q reads
//   - softmax: in-register via 64-lane shfl_xor butterflies; masked lanes
//     contribute exp(-inf)=0 and write P=0 (zero-padded rows)
//   - PV: fixed-40 fully unrolled loop, b128 broadcast P reads
// ---------------------------------------------------------------------------
__global__ __launch_bounds__(512) void k_topk_attn(
    const float* __restrict__ M, const float4* __restrict__ Q4,
    const float4* __restrict__ K4, const float4* __restrict__ V4,
    int* __restrict__ flags, float* __restrict__ upd)
{
    __shared__ unsigned long long cnd[NSEG * U];       // 320 candidates
    __shared__ int top_idx[U];
    __shared__ __align__(16) float Qs[U * 68];         // row-major, pad 68
    __shared__ __align__(16) float Kst[64 * 65];       // TRANSPOSED: [d*65+k]
    __shared__ __align__(16) float Vs[U * 68];         // row-major, pad 68
    __shared__ __align__(16) float Plds[U * 44];       // zero-padded rows

    int bh = blockIdx.x;
    int b = bh >> 3, h = bh & 7;
    int tid = threadIdx.x;
    int wv = tid >> 6, lane = tid & 63;

    // ---- phase A: per-segment exact top-40 by rank counting (1 wave/seg) ---
    int seg = wv;
    int j0 = seg * SEGL + lane * 4;

    // zero query flags for this segment (coalesced int4)
    *(int4*)(flags + (size_t)bh * L + j0) = make_int4(0, 0, 0, 0);

    float4 v = *(const float4*)(M + (size_t)bh * L + j0);
    unsigned m[4] = { mono(v.x), mono(v.y), mono(v.z), mono(v.w) };
    int rank[4] = { 0, 0, 0, 0 };

    #pragma unroll 4
    for (int src = 0; src < 64; ++src) {
        #pragma unroll
        for (int slot = 0; slot < 4; ++slot) {
            unsigned bm = __shfl(m[slot], src);
            int bj = src * 4 + slot;
            #pragma unroll
            for (int s = 0; s < 4; ++s) {
                int myj = lane * 4 + s;
                rank[s] += (bm > m[s]) || (bm == m[s] && bj < myj);
            }
        }
    }
    #pragma unroll
    for (int s = 0; s < 4; ++s)
        if (rank[s] < U)
            cnd[seg * U + rank[s]] = ((unsigned long long)m[s] << 32)
                                   | (unsigned)(~(unsigned)(j0 + s));
    __syncthreads();

    // ---- phase B: top-40 of 320, one candidate per thread, unrolled scan --
    if (tid < NSEG * U) {
        unsigned long long ka = cnd[tid];
        int ra = 0;
        #pragma unroll 8
        for (int j = 0; j < NSEG * U; ++j) ra += (cnd[j] > ka);
        if (ra < U) top_idx[ra] = (int)(~(unsigned)ka);
    }
    __syncthreads();

    if (tid < U) flags[bh * L + top_idx[tid]] = tid + 1;

    // ---- phase C: stage K (transposed), V, Q[top_idx[r]] ------------------
    for (int i = tid; i < U * 16; i += 512) {
        int r = i >> 4, d4 = i & 15;
        size_t kvbase = ((size_t)(b * L + r) * H + h) * 16 + d4;
        float4 kv = K4[kvbase];
        Kst[(4 * d4 + 0) * 65 + r] = kv.x;
        Kst[(4 * d4 + 1) * 65 + r] = kv.y;
        Kst[(4 * d4 + 2) * 65 + r] = kv.z;
        Kst[(4 * d4 + 3) * 65 + r] = kv.w;
        *(float4*)(Vs + r * 68 + d4 * 4) = V4[kvbase];
        *(float4*)(Qs + r * 68 + d4 * 4) =
            Q4[((size_t)(b * L + top_idx[r]) * H + h) * 16 + d4];
    }
    __syncthreads();

    // ---- phase D: scores + in-register softmax, wave-parallel -------------
    // wave wv owns rows 5*wv .. 5*wv+4; lane k = key index (k>=40 masked).
    const float scale = 0.125f;   // 1/sqrt(64)
    int k = lane;
    for (int rr = 0; rr < 5; ++rr) {
        int r = wv * 5 + rr;
        float acc = 0.f;
        #pragma unroll
        for (int d0 = 0; d0 < D; d0 += 4) {
            float4 qv = *(const float4*)(Qs + r * 68 + d0);   // broadcast
            acc += qv.x * Kst[(d0 + 0) * 65 + k];
            acc += qv.y * Kst[(d0 + 1) * 65 + k];
            acc += qv.z * Kst[(d0 + 2) * 65 + k];
            acc += qv.w * Kst[(d0 + 3) * 65 + k];
        }
        // causal over rank: keys k<=r only (k<=r implies k<40)
        float sc = (k <= r) ? acc * scale : -INFINITY;
        float mx = sc;
        #pragma unroll
        for (int off = 32; off >= 1; off >>= 1)
            mx = fmaxf(mx, __shfl_xor(mx, off));
        float e = __expf(sc - mx);            // masked lanes -> 0
        float sum = e;
        #pragma unroll
        for (int off = 32; off >= 1; off >>= 1)
            sum += __shfl_xor(sum, off);
        float p = e / sum;
        if (k < U) Plds[r * 44 + k] = p;      // zeros where masked
    }
    __syncthreads();

    // ---- phase E: PV, fixed-40 fully unrolled --------------------------
    for (int t = tid; t < U * D; t += 512) {
        int r = t >> 6, d = t & 63;
        float acc = 0.f;
        #pragma unroll
        for (int kk = 0; kk < U; kk += 4) {
            float4 pv = *(const float4*)(Plds + r * 44 + kk);  // broadcast
            acc += pv.x * Vs[(kk + 0) * 68 + d];
            acc += pv.y * Vs[(kk + 1) * 68 + d];
            acc += pv.z * Vs[(kk + 2) * 68 + d];
            acc += pv.w * Vs[(kk + 3) * 68 + d];
        }
        upd[((size_t)bh * U + r) * D + d] = acc;
    }
}

// ---------------------------------------------------------------------------
// K3: per-chunk sums of V along L (totals only, NOT scanned).
// ---------------------------------------------------------------------------
__global__ __launch_bounds__(512) void k_chunksum(
    const float* __restrict__ V, float* __restrict__ partial)
{
    int b = blockIdx.x >> 6;        // NC = 64
    int c = blockIdx.x & 63;
    int hd = threadIdx.x;
    const float* vp = V + ((size_t)(b * L + c * CL)) * HD + hd;
    float s = 0.f;
    #pragma unroll
    for (int l = 0; l < CL; ++l) s += vp[(size_t)l * HD];
    partial[((size_t)b * NC + c) * HD + hd] = s;
}

// ---------------------------------------------------------------------------
// K4: emit. Each block (b,c) computes its exclusive prefix by summing the
// c predecessor chunk totals (512 KB of partials -> L2-resident, redundant
// but cheap and deadlock-free), then emits cumsum with flagged rows
// replaced by upd. Ordering is purely by dispatch boundaries - no
// inter-block waiting anywhere.
// ---------------------------------------------------------------------------
__global__ __launch_bounds__(512) void k_out(
    const float* __restrict__ V, const float* __restrict__ partial,
    const int* __restrict__ flags, const float* __restrict__ upd,
    float* __restrict__ out)
{
    int b = blockIdx.x >> 6;
    int c = blockIdx.x & 63;
    int hd = threadIdx.x;
    int h = hd >> 6, d = hd & 63;

    // exclusive prefix over predecessor chunk totals
    float acc = 0.f;
    const float* pp = partial + (size_t)b * NC * HD + hd;
    for (int j = 0; j < c; ++j) acc += pp[(size_t)j * HD];

    const float* vp = V + ((size_t)(b * L + c * CL)) * HD + hd;
    float*       op = out + ((size_t)(b * L + c * CL)) * HD + hd;
    const int*   fp = flags + (b * H + h) * L + c * CL;
    const float* up = upd + (size_t)(b * H + h) * U * D + d;

    #pragma unroll 4
    for (int l = 0; l < CL; ++l) {
        acc += vp[(size_t)l * HD];
        int f = fp[l];
        float o = f ? up[(size_t)(f - 1) * D] : acc;
        __builtin_nontemporal_store(o, op + (size_t)l * HD);
    }
}

extern "C" void kernel_launch(void* const* d_in, const int* in_sizes, int n_in,
                              void* d_out, int out_size, void* d_ws, size_t ws_size,
                              hipStream_t stream)
{
    const float* Q   = (const float*)d_in[0];
    const float* K   = (const float*)d_in[1];
    const float* V   = (const float*)d_in[2];
    const int*  idxs = (const int*)d_in[3];
    float* out = (float*)d_out;

    char* ws = (char*)d_ws;
    float* M        = (float*)(ws);                 // B*H*L          = 256 KB
    int*   flags    = (int*)  (ws + 262144);        // B*H*L          = 256 KB
    float* upd      = (float*)(ws + 524288);        // B*H*U*D        = 320 KB
    float* partial  = (float*)(ws + 851968);        // B*NC*HD        = 512 KB

    k_scores    <<<B * L / 4, 256, 0, stream>>>((const float4*)Q, (const float4*)K, idxs, M);
    k_topk_attn <<<B * H,     512, 0, stream>>>(M, (const float4*)Q, (const float4*)K,
                                                (const float4*)V, flags, upd);
    k_chunksum  <<<B * NC,    512, 0, stream>>>(V, partial);
    k_out       <<<B * NC,    512, 0, stream>>>(V, partial, flags, upd, out);
}